// Round 2
// baseline (775.290 us; speedup 1.0000x reference)
//
#include <hip/hip_runtime.h>
#include <hip/hip_bf16.h>
#include <cstdint>
#include <cstddef>

// Problem constants
#define HW   512
#define HW2  1024
#define SZ   (512 * 512)
#define NPT  (34 * 34)   // 1156 warped 1024-res points per 16x16 output tile
#define K_PTS 5          // ceil(1156 / 256)
#define SRCW 36          // staged source window: 36x36
#define SRCP 37          // padded LDS row stride (odd -> bank rotation across rows)
#define NSRC (SRCW * SRCW)   // 1296 logical elements
#define MARG 9           // window origin = tile_origin - MARG

// jax.image.resize bilinear upsample 512->1024 taps for output index i (0..1023)
struct UpTap { int i0, i1; float w0, w1; };

__device__ __forceinline__ UpTap up_tap(int i) {
  UpTap t;
  int k = i >> 1;
  if ((i & 1) == 0) {
    t.i0 = k - 1; t.i1 = k; t.w0 = 0.25f; t.w1 = 0.75f;
    if (k == 0) { t.i0 = 0; t.w0 = 0.0f; t.w1 = 1.0f; }
  } else {
    t.i0 = k; t.i1 = k + 1; t.w0 = 0.75f; t.w1 = 0.25f;
    if (k == HW - 1) { t.i1 = HW - 1; t.w0 = 1.0f; t.w1 = 0.0f; }
  }
  return t;
}

__device__ __forceinline__ float up_at(const float* __restrict__ plane, int yi, int xi) {
  UpTap ty = up_tap(yi), tx = up_tap(xi);
  const float* r0 = plane + (size_t)ty.i0 * HW;
  const float* r1 = plane + (size_t)ty.i1 * HW;
  float v00 = r0[tx.i0], v01 = r0[tx.i1];
  float v10 = r1[tx.i0], v11 = r1[tx.i1];
  return ty.w0 * (tx.w0 * v00 + tx.w1 * v01) + ty.w1 * (tx.w0 * v10 + tx.w1 * v11);
}

// Separable decomposition of (warp-bilinear in 1024-space) o (2x upsample):
// a 3-tap stencil on the 512 grid.
__device__ __forceinline__ void axis_taps(float s, int& base, float& w0, float& w1, float& w2) {
  float f0 = floorf(s);
  int i0 = (int)f0;
  float fr = s - f0;
  int b = (i0 & 1) ? (i0 >> 1) : (i0 >> 1) - 1;
  b = b < 0 ? 0 : (b > (HW - 3) ? (HW - 3) : b);
  float w[3] = {0.0f, 0.0f, 0.0f};
  if ((unsigned)i0 < (unsigned)HW2) {
    UpTap t = up_tap(i0);
    w[t.i0 - b] += (1.0f - fr) * t.w0;
    w[t.i1 - b] += (1.0f - fr) * t.w1;
  }
  if ((unsigned)(i0 + 1) < (unsigned)HW2) {
    UpTap t = up_tap(i0 + 1);
    w[t.i0 - b] += fr * t.w0;
    w[t.i1 - b] += fr * t.w1;
  }
  base = b; w0 = w[0]; w1 = w[1]; w2 = w[2];
}

// -------------------- K0: copy src channels (0..15) straight to output --------------------
__global__ void copy_src_kernel(const float* __restrict__ x, float* __restrict__ out) {
  const size_t half = (size_t)16 * SZ;
  const size_t nvec = half / 4;                 // float4
  size_t i = (size_t)blockIdx.x * blockDim.x + threadIdx.x;
  if (i < 2 * nvec) {
    size_t b = i / nvec, j = i % nvec;
    const float4* s = (const float4*)(x + b * 2 * half);
    float4* d = (float4*)(out + b * 2 * half);
    d[j] = s[j];
  }
}

// Per-point separable 3x3 stencil. locoff >= 0: index into staged (padded) LDS window.
// locoff < 0: rare fallback, ~locoff = global by*HW+bx offset (displacement > ~8px).
struct PtTaps {
  int   locoff;
  float wy0, wy1, wy2, wx0, wx1, wx2;
};

__device__ __forceinline__ void compute_taps(const float* __restrict__ fx,
                                             const float* __restrict__ fy,
                                             int gx0, int gy0, int xo, int yo, int tid,
                                             PtTaps (&pt)[K_PTS]) {
  #pragma unroll
  for (int i = 0; i < K_PTS; ++i) {
    int p = tid + i * 256;
    pt[i].locoff = 0;
    pt[i].wy0 = pt[i].wy1 = pt[i].wy2 = 0.0f;
    pt[i].wx0 = pt[i].wx1 = pt[i].wx2 = 0.0f;
    if (p < NPT) {
      int ry = p / 34, rx = p % 34;
      int yy = gy0 + ry, xx = gx0 + rx;
      if ((unsigned)yy < (unsigned)HW2 && (unsigned)xx < (unsigned)HW2) {
        float sx = (float)xx + 2.0f * up_at(fx, yy, xx);
        float sy = (float)yy + 2.0f * up_at(fy, yy, xx);
        int bx, by;
        axis_taps(sx, bx, pt[i].wx0, pt[i].wx1, pt[i].wx2);
        axis_taps(sy, by, pt[i].wy0, pt[i].wy1, pt[i].wy2);
        int rx_ = bx - xo, ry_ = by - yo;
        if ((unsigned)rx_ <= (unsigned)(SRCW - 3) && (unsigned)ry_ <= (unsigned)(SRCW - 3))
          pt[i].locoff = ry_ * SRCP + rx_;          // in staged window (padded stride)
        else
          pt[i].locoff = ~(by * HW + bx);           // fallback: global offset
      }
    }
  }
}

// Stage a channel pair's 36x36 source window into SoA LDS (padded rows).
__device__ __forceinline__ void stage_pair(const float* __restrict__ p0,
                                           const float* __restrict__ p1,
                                           float* __restrict__ s0,
                                           float* __restrict__ s1,
                                           int xo, int yo, int tid) {
  #pragma unroll
  for (int i = 0; i < 6; ++i) {                   // 6*256 = 1536 >= 1296
    int p = tid + i * 256;
    if (p < NSRC) {
      int r = p / SRCW, c = p % SRCW;
      int gy = yo + r; gy = gy < 0 ? 0 : (gy > HW - 1 ? HW - 1 : gy);
      int gx = xo + c; gx = gx < 0 ? 0 : (gx > HW - 1 ? HW - 1 : gx);
      size_t o = (size_t)gy * HW + gx;
      int d = r * SRCP + c;
      s0[d] = p0[o];
      s1[d] = p1[o];
    }
  }
}

__device__ __forceinline__ float eval3_global(const float* __restrict__ pl, int off, const PtTaps& t) {
  const float* p0 = pl + off;
  float r0 = t.wx0 * p0[0]        + t.wx1 * p0[1]          + t.wx2 * p0[2];
  float r1 = t.wx0 * p0[HW]       + t.wx1 * p0[HW + 1]     + t.wx2 * p0[HW + 2];
  float r2 = t.wx0 * p0[2 * HW]   + t.wx1 * p0[2 * HW + 1] + t.wx2 * p0[2 * HW + 2];
  return t.wy0 * r0 + t.wy1 * r1 + t.wy2 * r2;
}

// Evaluate all points of a channel pair from staged SoA LDS windows into SoA tiles.
__device__ __forceinline__ void eval_round(const float* __restrict__ s0,
                                           const float* __restrict__ s1,
                                           float* __restrict__ t0,
                                           float* __restrict__ t1,
                                           const float* __restrict__ plane0,
                                           const float* __restrict__ plane1,
                                           const PtTaps (&pt)[K_PTS], int tid) {
  #pragma unroll
  for (int i = 0; i < K_PTS; ++i) {
    int p = tid + i * 256;
    if (p < NPT) {
      const PtTaps t = pt[i];
      float a0, a1;
      if (t.locoff >= 0) {
        const float* a = s0 + t.locoff;
        const float* b = s1 + t.locoff;
        float r00 = t.wx0 * a[0]        + t.wx1 * a[1]            + t.wx2 * a[2];
        float r10 = t.wx0 * a[SRCP]     + t.wx1 * a[SRCP + 1]     + t.wx2 * a[SRCP + 2];
        float r20 = t.wx0 * a[2 * SRCP] + t.wx1 * a[2 * SRCP + 1] + t.wx2 * a[2 * SRCP + 2];
        float r01 = t.wx0 * b[0]        + t.wx1 * b[1]            + t.wx2 * b[2];
        float r11 = t.wx0 * b[SRCP]     + t.wx1 * b[SRCP + 1]     + t.wx2 * b[SRCP + 2];
        float r21 = t.wx0 * b[2 * SRCP] + t.wx1 * b[2 * SRCP + 1] + t.wx2 * b[2 * SRCP + 2];
        a0 = t.wy0 * r00 + t.wy1 * r10 + t.wy2 * r20;
        a1 = t.wy0 * r01 + t.wy1 * r11 + t.wy2 * r21;
      } else {                                     // ~never taken (|disp| > ~8px)
        int off = ~t.locoff;
        a0 = eval3_global(plane0, off, t);
        a1 = eval3_global(plane1, off, t);
      }
      t0[p] = a0;
      t1[p] = a1;
    }
  }
}

// -------------------- K1/K4: res_warp_img(tgt, res_field, rollback=1) --------------------
__global__ void __launch_bounds__(256, 8)
warp_img_kernel(const float* __restrict__ x,    // [B,32,512,512]
                const float* __restrict__ res,  // [B,2,512,512]
                float* __restrict__ out)        // [B,32,512,512]
{
  __shared__ float s_src0[36 * SRCP];  // 5328 B each
  __shared__ float s_src1[36 * SRCP];
  __shared__ float s_tile0[NPT];       // 4624 B each
  __shared__ float s_tile1[NPT];       // total 19904 B -> 8 blocks/CU

  const int b = blockIdx.z;
  const int tx0 = blockIdx.x * 16, ty0 = blockIdx.y * 16;
  const int gx0 = tx0 * 2 - 1, gy0 = ty0 * 2 - 1;
  const int xo = tx0 - MARG, yo = ty0 - MARG;
  const int tid = threadIdx.x;

  const float* resx = res + (size_t)b * 2 * SZ;
  const float* resy = resx + SZ;
  const float* tgt  = x + ((size_t)b * 32 + 16) * SZ;

  // Issue staging loads for round 0 first so they fly under tap computation.
  stage_pair(tgt, tgt + SZ, s_src0, s_src1, xo, yo, tid);

  PtTaps pt[K_PTS];
  compute_taps(resx, resy, gx0, gy0, xo, yo, tid, pt);

  const int ly = tid >> 4, lx = tid & 15;
  const int oy = ty0 + ly, ox = tx0 + lx;
  const float RW[4] = {0.25f, 0.75f, 0.75f, 0.25f};
  float wy[4], wx[4];
  float sumy = 0.f, sumx = 0.f;
  #pragma unroll
  for (int d = 0; d < 4; ++d) {
    int g = 2 * oy - 1 + d;
    wy[d] = ((unsigned)g < (unsigned)HW2) ? RW[d] : 0.0f; sumy += wy[d];
    g = 2 * ox - 1 + d;
    wx[d] = ((unsigned)g < (unsigned)HW2) ? RW[d] : 0.0f; sumx += wx[d];
  }
  const float inv = 1.0f / (sumy * sumx);

  __syncthreads();                                 // s_src round 0 ready

  for (int c = 0; c < 16; c += 2) {
    const float* plane0 = tgt + (size_t)c * SZ;
    eval_round(s_src0, s_src1, s_tile0, s_tile1, plane0, plane0 + SZ, pt, tid);
    __syncthreads();                               // s_tile ready; s_src free

    if (c < 14)                                    // overlap next staging with phase 3
      stage_pair(plane0 + 2 * SZ, plane0 + 3 * SZ, s_src0, s_src1, xo, yo, tid);

    float acc0 = 0.0f, acc1 = 0.0f;
    #pragma unroll
    for (int dy = 0; dy < 4; ++dy) {
      float r0 = 0.0f, r1 = 0.0f;
      const int base = (2 * ly + dy) * 34 + 2 * lx;
      #pragma unroll
      for (int dx = 0; dx < 4; ++dx) {
        r0 += wx[dx] * s_tile0[base + dx];
        r1 += wx[dx] * s_tile1[base + dx];
      }
      acc0 += wy[dy] * r0;
      acc1 += wy[dy] * r1;
    }
    size_t o = (((size_t)b * 32 + 16 + c) * HW + oy) * HW + ox;
    out[o] = acc0 * inv;
    out[o + SZ] = acc1 * inv;
    __syncthreads();                               // s_src(next) ready; s_tile free
  }
}

// -------------------- K2: 3x3 conv over 50-ch bundle -> 2-ch adj --------------------
// LDS-staged halo (zero-filled), double-buffered with register round-trip (T14 split):
// loads for plane ic+1 issue right after the barrier; ds_writes land after compute(ic),
// so HBM latency hides under the 18-FMA compute phase. No per-tap bounds branches.
#define CHN 18                     // halo width (16 + 2)
#define CHE (CHN * CHN)            // 324 elements

__global__ void __launch_bounds__(256)
conv_kernel(const float* __restrict__ x,
            const float* __restrict__ warped,  // = out, ch 16..31
            const float* __restrict__ res,
            const float* __restrict__ Wc,      // [2,50,3,3]
            const float* __restrict__ bc,      // [2]
            float* __restrict__ adj)           // [B,2,512,512]
{
  __shared__ float sw[900];
  __shared__ float sh[2][CHE];

  const int tid = threadIdx.x;
  for (int i = tid; i < 900; i += 256) sw[i] = Wc[i];

  const int b = blockIdx.z;
  const int tx0 = blockIdx.x * 16, ty0 = blockIdx.y * 16;
  const int ty = tid >> 4, tx = tid & 15;

  float acc0 = bc[0];
  float acc1 = bc[1];

  const float* px = x + (size_t)b * 32 * SZ;
  const float* pw = warped + ((size_t)b * 32 + 16) * SZ;
  const float* pr = res + (size_t)b * 2 * SZ;

  // plane base for input-channel ic of the 50-ch bundle
  #define PLANE(ic) ((ic) < 32 ? px + (size_t)(ic) * SZ \
                   : (ic) < 48 ? pw + (size_t)((ic) - 32) * SZ \
                   : pr + (size_t)((ic) - 48) * SZ)

  float rb0, rb1;
  {  // stage plane 0
    const float* pl = PLANE(0);
    rb0 = 0.f; rb1 = 0.f;
    int p = tid;
    { int ry = p / CHN, rx = p % CHN;
      int gy = ty0 - 1 + ry, gx = tx0 - 1 + rx;
      if ((unsigned)gy < (unsigned)HW && (unsigned)gx < (unsigned)HW) rb0 = pl[(size_t)gy * HW + gx]; }
    p = tid + 256;
    if (p < CHE) {
      int ry = p / CHN, rx = p % CHN;
      int gy = ty0 - 1 + ry, gx = tx0 - 1 + rx;
      if ((unsigned)gy < (unsigned)HW && (unsigned)gx < (unsigned)HW) rb1 = pl[(size_t)gy * HW + gx];
    }
    sh[0][tid] = rb0;
    if (tid + 256 < CHE) sh[0][tid + 256] = rb1;
  }

  for (int ic = 0; ic < 50; ++ic) {
    __syncthreads();                      // sh[ic&1] ready (and prev writes drained)
    // issue next plane's loads (registers) before compute
    if (ic < 49) {
      const float* pl = PLANE(ic + 1);
      rb0 = 0.f; rb1 = 0.f;
      int p = tid;
      { int ry = p / CHN, rx = p % CHN;
        int gy = ty0 - 1 + ry, gx = tx0 - 1 + rx;
        if ((unsigned)gy < (unsigned)HW && (unsigned)gx < (unsigned)HW) rb0 = pl[(size_t)gy * HW + gx]; }
      p = tid + 256;
      if (p < CHE) {
        int ry = p / CHN, rx = p % CHN;
        int gy = ty0 - 1 + ry, gx = tx0 - 1 + rx;
        if ((unsigned)gy < (unsigned)HW && (unsigned)gx < (unsigned)HW) rb1 = pl[(size_t)gy * HW + gx];
      }
    }

    const float* hp = sh[ic & 1];
    const float* w0 = &sw[ic * 9];
    const float* w1 = &sw[450 + ic * 9];
    #pragma unroll
    for (int ky = 0; ky < 3; ++ky) {
      #pragma unroll
      for (int kx = 0; kx < 3; ++kx) {
        float v = hp[(ty + ky) * CHN + tx + kx];
        acc0 += v * w0[ky * 3 + kx];
        acc1 += v * w1[ky * 3 + kx];
      }
    }

    if (ic < 49) {                        // write-late into the other buffer
      float* sd = sh[(ic + 1) & 1];
      sd[tid] = rb0;
      if (tid + 256 < CHE) sd[tid + 256] = rb1;
    }
  }
  #undef PLANE

  const int oy = ty0 + ty, ox = tx0 + tx;
  adj[((size_t)b * 2 + 0) * SZ + (size_t)oy * HW + ox] = acc0;
  adj[((size_t)b * 2 + 1) * SZ + (size_t)oy * HW + ox] = acc1;
}

// -------------------- K3: new_res = adj + downsample(warp(up(res), 2*up(adj))) --------------------
__global__ void __launch_bounds__(256, 8)
new_res_kernel(const float* __restrict__ res,  // [B,2,512,512]
               const float* __restrict__ adj,  // [B,2,512,512]
               float* __restrict__ nres)       // [B,2,512,512]
{
  __shared__ float s_src0[36 * SRCP];
  __shared__ float s_src1[36 * SRCP];
  __shared__ float s_tile0[NPT];
  __shared__ float s_tile1[NPT];

  const int b = blockIdx.z;
  const int tx0 = blockIdx.x * 16, ty0 = blockIdx.y * 16;
  const int gx0 = tx0 * 2 - 1, gy0 = ty0 * 2 - 1;
  const int xo = tx0 - MARG, yo = ty0 - MARG;
  const int tid = threadIdx.x;

  const float* adjx = adj + (size_t)b * 2 * SZ;
  const float* adjy = adjx + SZ;
  const float* res0 = res + (size_t)b * 2 * SZ;
  const float* res1 = res0 + SZ;

  stage_pair(res0, res1, s_src0, s_src1, xo, yo, tid);

  PtTaps pt[K_PTS];
  compute_taps(adjx, adjy, gx0, gy0, xo, yo, tid, pt);

  const int ly = tid >> 4, lx = tid & 15;
  const int oy = ty0 + ly, ox = tx0 + lx;
  const float RW[4] = {0.25f, 0.75f, 0.75f, 0.25f};
  float wy[4], wx[4];
  float sumy = 0.f, sumx = 0.f;
  #pragma unroll
  for (int d = 0; d < 4; ++d) {
    int g = 2 * oy - 1 + d;
    wy[d] = ((unsigned)g < (unsigned)HW2) ? RW[d] : 0.0f; sumy += wy[d];
    g = 2 * ox - 1 + d;
    wx[d] = ((unsigned)g < (unsigned)HW2) ? RW[d] : 0.0f; sumx += wx[d];
  }
  const float inv = 1.0f / (sumy * sumx);

  __syncthreads();
  eval_round(s_src0, s_src1, s_tile0, s_tile1, res0, res1, pt, tid);
  __syncthreads();

  float acc0 = 0.0f, acc1 = 0.0f;
  #pragma unroll
  for (int dy = 0; dy < 4; ++dy) {
    float r0 = 0.0f, r1 = 0.0f;
    const int base = (2 * ly + dy) * 34 + 2 * lx;
    #pragma unroll
    for (int dx = 0; dx < 4; ++dx) {
      r0 += wx[dx] * s_tile0[base + dx];
      r1 += wx[dx] * s_tile1[base + dx];
    }
    acc0 += wy[dy] * r0;
    acc1 += wy[dy] * r1;
  }
  size_t o = ((size_t)b * 2) * SZ + (size_t)oy * HW + ox;
  nres[o]      = acc0 * inv + adjx[(size_t)oy * HW + ox];
  nres[o + SZ] = acc1 * inv + adjy[(size_t)oy * HW + ox];
}

extern "C" void kernel_launch(void* const* d_in, const int* in_sizes, int n_in,
                              void* d_out, int out_size, void* d_ws, size_t ws_size,
                              hipStream_t stream) {
  const float* x   = (const float*)d_in[0];  // [2,32,512,512] f32
  const float* res = (const float*)d_in[1];  // [2,2,512,512]  f32
  const float* Wc  = (const float*)d_in[2];  // [2,50,3,3]     f32
  const float* bc  = (const float*)d_in[3];  // [2]            f32
  float* out = (float*)d_out;                // [2,32,512,512] f32

  float* adj  = (float*)d_ws;                // [2,2,512,512]
  float* nres = adj + (size_t)2 * 2 * SZ;    // [2,2,512,512]

  // K0: src passthrough (out channels 0..15 per batch)
  {
    const size_t nvec = 2 * ((size_t)16 * SZ / 4);
    copy_src_kernel<<<dim3((unsigned)((nvec + 255) / 256)), dim3(256), 0, stream>>>(x, out);
  }

  dim3 tile_grid(32, 32, 2);

  // K1: warped_tgt (stage A) -> out channels 16..31 (fp32 staging for conv)
  warp_img_kernel<<<tile_grid, dim3(256), 0, stream>>>(x, res, out);

  // K2: conv3x3 over [x(0..31) | out(16..31) | res] -> adj
  conv_kernel<<<tile_grid, dim3(256), 0, stream>>>(x, out, res, Wc, bc, adj);

  // K3: new_res
  new_res_kernel<<<tile_grid, dim3(256), 0, stream>>>(res, adj, nres);

  // K4: hindsight warp -> out channels 16..31 (overwrites staging)
  warp_img_kernel<<<tile_grid, dim3(256), 0, stream>>>(x, nres, out);
}

// Round 3
// 408.749 us; speedup vs baseline: 1.8967x; 1.8967x over previous
//
#include <hip/hip_runtime.h>
#include <hip/hip_bf16.h>
#include <cstdint>
#include <cstddef>

// Problem constants
#define HW   512
#define HW2  1024
#define SZ   (512 * 512)
#define NPT  (34 * 34)   // 1156 warped 1024-res points per 16x16 output tile
#define K_PTS 5          // ceil(1156 / 256)
#define SRCW 36          // staged source window: 36x36
#define SRCP 37          // padded LDS row stride (odd -> bank rotation across rows)
#define NSRC (SRCW * SRCW)   // 1296 logical elements
#define MARG 9           // window origin = tile_origin - MARG

// jax.image.resize bilinear upsample 512->1024 taps for output index i (0..1023)
struct UpTap { int i0, i1; float w0, w1; };

__device__ __forceinline__ UpTap up_tap(int i) {
  UpTap t;
  int k = i >> 1;
  if ((i & 1) == 0) {
    t.i0 = k - 1; t.i1 = k; t.w0 = 0.25f; t.w1 = 0.75f;
    if (k == 0) { t.i0 = 0; t.w0 = 0.0f; t.w1 = 1.0f; }
  } else {
    t.i0 = k; t.i1 = k + 1; t.w0 = 0.75f; t.w1 = 0.25f;
    if (k == HW - 1) { t.i1 = HW - 1; t.w0 = 1.0f; t.w1 = 0.0f; }
  }
  return t;
}

__device__ __forceinline__ float up_at(const float* __restrict__ plane, int yi, int xi) {
  UpTap ty = up_tap(yi), tx = up_tap(xi);
  const float* r0 = plane + (size_t)ty.i0 * HW;
  const float* r1 = plane + (size_t)ty.i1 * HW;
  float v00 = r0[tx.i0], v01 = r0[tx.i1];
  float v10 = r1[tx.i0], v11 = r1[tx.i1];
  return ty.w0 * (tx.w0 * v00 + tx.w1 * v01) + ty.w1 * (tx.w0 * v10 + tx.w1 * v11);
}

// Separable decomposition of (warp-bilinear in 1024-space) o (2x upsample):
// a 3-tap stencil on the 512 grid.
__device__ __forceinline__ void axis_taps(float s, int& base, float& w0, float& w1, float& w2) {
  float f0 = floorf(s);
  int i0 = (int)f0;
  float fr = s - f0;
  int b = (i0 & 1) ? (i0 >> 1) : (i0 >> 1) - 1;
  b = b < 0 ? 0 : (b > (HW - 3) ? (HW - 3) : b);
  float w[3] = {0.0f, 0.0f, 0.0f};
  if ((unsigned)i0 < (unsigned)HW2) {
    UpTap t = up_tap(i0);
    w[t.i0 - b] += (1.0f - fr) * t.w0;
    w[t.i1 - b] += (1.0f - fr) * t.w1;
  }
  if ((unsigned)(i0 + 1) < (unsigned)HW2) {
    UpTap t = up_tap(i0 + 1);
    w[t.i0 - b] += fr * t.w0;
    w[t.i1 - b] += fr * t.w1;
  }
  base = b; w0 = w[0]; w1 = w[1]; w2 = w[2];
}

// -------------------- K0: copy src channels (0..15) straight to output --------------------
__global__ void copy_src_kernel(const float* __restrict__ x, float* __restrict__ out) {
  const size_t half = (size_t)16 * SZ;
  const size_t nvec = half / 4;                 // float4
  size_t i = (size_t)blockIdx.x * blockDim.x + threadIdx.x;
  if (i < 2 * nvec) {
    size_t b = i / nvec, j = i % nvec;
    const float4* s = (const float4*)(x + b * 2 * half);
    float4* d = (float4*)(out + b * 2 * half);
    d[j] = s[j];
  }
}

// Per-point separable 3x3 stencil. locoff >= 0: index into staged (padded) LDS window.
// locoff < 0: rare fallback, ~locoff = global by*HW+bx offset (displacement > ~8px).
struct PtTaps {
  int   locoff;
  float wy0, wy1, wy2, wx0, wx1, wx2;
};

__device__ __forceinline__ void compute_taps(const float* __restrict__ fx,
                                             const float* __restrict__ fy,
                                             int gx0, int gy0, int xo, int yo, int tid,
                                             PtTaps (&pt)[K_PTS]) {
  #pragma unroll
  for (int i = 0; i < K_PTS; ++i) {
    int p = tid + i * 256;
    pt[i].locoff = 0;
    pt[i].wy0 = pt[i].wy1 = pt[i].wy2 = 0.0f;
    pt[i].wx0 = pt[i].wx1 = pt[i].wx2 = 0.0f;
    if (p < NPT) {
      int ry = p / 34, rx = p % 34;
      int yy = gy0 + ry, xx = gx0 + rx;
      if ((unsigned)yy < (unsigned)HW2 && (unsigned)xx < (unsigned)HW2) {
        float sx = (float)xx + 2.0f * up_at(fx, yy, xx);
        float sy = (float)yy + 2.0f * up_at(fy, yy, xx);
        int bx, by;
        axis_taps(sx, bx, pt[i].wx0, pt[i].wx1, pt[i].wx2);
        axis_taps(sy, by, pt[i].wy0, pt[i].wy1, pt[i].wy2);
        int rx_ = bx - xo, ry_ = by - yo;
        if ((unsigned)rx_ <= (unsigned)(SRCW - 3) && (unsigned)ry_ <= (unsigned)(SRCW - 3))
          pt[i].locoff = ry_ * SRCP + rx_;          // in staged window (padded stride)
        else
          pt[i].locoff = ~(by * HW + bx);           // fallback: global offset
      }
    }
  }
}

// Stage a channel pair's 36x36 source window into SoA LDS (padded rows).
__device__ __forceinline__ void stage_pair(const float* __restrict__ p0,
                                           const float* __restrict__ p1,
                                           float* __restrict__ s0,
                                           float* __restrict__ s1,
                                           int xo, int yo, int tid) {
  #pragma unroll
  for (int i = 0; i < 6; ++i) {                   // 6*256 = 1536 >= 1296
    int p = tid + i * 256;
    if (p < NSRC) {
      int r = p / SRCW, c = p % SRCW;
      int gy = yo + r; gy = gy < 0 ? 0 : (gy > HW - 1 ? HW - 1 : gy);
      int gx = xo + c; gx = gx < 0 ? 0 : (gx > HW - 1 ? HW - 1 : gx);
      size_t o = (size_t)gy * HW + gx;
      int d = r * SRCP + c;
      s0[d] = p0[o];
      s1[d] = p1[o];
    }
  }
}

__device__ __forceinline__ float eval3_global(const float* __restrict__ pl, int off, const PtTaps& t) {
  const float* p0 = pl + off;
  float r0 = t.wx0 * p0[0]        + t.wx1 * p0[1]          + t.wx2 * p0[2];
  float r1 = t.wx0 * p0[HW]       + t.wx1 * p0[HW + 1]     + t.wx2 * p0[HW + 2];
  float r2 = t.wx0 * p0[2 * HW]   + t.wx1 * p0[2 * HW + 1] + t.wx2 * p0[2 * HW + 2];
  return t.wy0 * r0 + t.wy1 * r1 + t.wy2 * r2;
}

// Evaluate all points of a channel pair from staged SoA LDS windows into SoA tiles.
__device__ __forceinline__ void eval_round(const float* __restrict__ s0,
                                           const float* __restrict__ s1,
                                           float* __restrict__ t0,
                                           float* __restrict__ t1,
                                           const float* __restrict__ plane0,
                                           const float* __restrict__ plane1,
                                           const PtTaps (&pt)[K_PTS], int tid) {
  #pragma unroll
  for (int i = 0; i < K_PTS; ++i) {
    int p = tid + i * 256;
    if (p < NPT) {
      const PtTaps t = pt[i];
      float a0, a1;
      if (t.locoff >= 0) {
        const float* a = s0 + t.locoff;
        const float* b = s1 + t.locoff;
        float r00 = t.wx0 * a[0]        + t.wx1 * a[1]            + t.wx2 * a[2];
        float r10 = t.wx0 * a[SRCP]     + t.wx1 * a[SRCP + 1]     + t.wx2 * a[SRCP + 2];
        float r20 = t.wx0 * a[2 * SRCP] + t.wx1 * a[2 * SRCP + 1] + t.wx2 * a[2 * SRCP + 2];
        float r01 = t.wx0 * b[0]        + t.wx1 * b[1]            + t.wx2 * b[2];
        float r11 = t.wx0 * b[SRCP]     + t.wx1 * b[SRCP + 1]     + t.wx2 * b[SRCP + 2];
        float r21 = t.wx0 * b[2 * SRCP] + t.wx1 * b[2 * SRCP + 1] + t.wx2 * b[2 * SRCP + 2];
        a0 = t.wy0 * r00 + t.wy1 * r10 + t.wy2 * r20;
        a1 = t.wy0 * r01 + t.wy1 * r11 + t.wy2 * r21;
      } else {                                     // ~never taken (|disp| > ~8px)
        int off = ~t.locoff;
        a0 = eval3_global(plane0, off, t);
        a1 = eval3_global(plane1, off, t);
      }
      t0[p] = a0;
      t1[p] = a1;
    }
  }
}

// -------------------- K1/K4: res_warp_img(tgt, res_field, rollback=1) --------------------
// NOTE: no min-waves bound — (256,8) forced VGPR<=64 and spilled pt[] to scratch
// (round 2: VGPR 32, FETCH 764MB, 2.6x slower). Natural VGPR ~80, 4 blocks/CU is fine.
__global__ void __launch_bounds__(256)
warp_img_kernel(const float* __restrict__ x,    // [B,32,512,512]
                const float* __restrict__ res,  // [B,2,512,512]
                float* __restrict__ out)        // [B,32,512,512]
{
  __shared__ float s_src0[36 * SRCP];  // 5328 B each
  __shared__ float s_src1[36 * SRCP];
  __shared__ float s_tile0[NPT];       // 4624 B each
  __shared__ float s_tile1[NPT];

  const int b = blockIdx.z;
  const int tx0 = blockIdx.x * 16, ty0 = blockIdx.y * 16;
  const int gx0 = tx0 * 2 - 1, gy0 = ty0 * 2 - 1;
  const int xo = tx0 - MARG, yo = ty0 - MARG;
  const int tid = threadIdx.x;

  const float* resx = res + (size_t)b * 2 * SZ;
  const float* resy = resx + SZ;
  const float* tgt  = x + ((size_t)b * 32 + 16) * SZ;

  // Issue staging loads for round 0 first so they fly under tap computation.
  stage_pair(tgt, tgt + SZ, s_src0, s_src1, xo, yo, tid);

  PtTaps pt[K_PTS];
  compute_taps(resx, resy, gx0, gy0, xo, yo, tid, pt);

  const int ly = tid >> 4, lx = tid & 15;
  const int oy = ty0 + ly, ox = tx0 + lx;
  const float RW[4] = {0.25f, 0.75f, 0.75f, 0.25f};
  float wy[4], wx[4];
  float sumy = 0.f, sumx = 0.f;
  #pragma unroll
  for (int d = 0; d < 4; ++d) {
    int g = 2 * oy - 1 + d;
    wy[d] = ((unsigned)g < (unsigned)HW2) ? RW[d] : 0.0f; sumy += wy[d];
    g = 2 * ox - 1 + d;
    wx[d] = ((unsigned)g < (unsigned)HW2) ? RW[d] : 0.0f; sumx += wx[d];
  }
  const float inv = 1.0f / (sumy * sumx);

  __syncthreads();                                 // s_src round 0 ready

  for (int c = 0; c < 16; c += 2) {
    const float* plane0 = tgt + (size_t)c * SZ;
    eval_round(s_src0, s_src1, s_tile0, s_tile1, plane0, plane0 + SZ, pt, tid);
    __syncthreads();                               // s_tile ready; s_src free

    if (c < 14)                                    // overlap next staging with phase 3
      stage_pair(plane0 + 2 * SZ, plane0 + 3 * SZ, s_src0, s_src1, xo, yo, tid);

    float acc0 = 0.0f, acc1 = 0.0f;
    #pragma unroll
    for (int dy = 0; dy < 4; ++dy) {
      float r0 = 0.0f, r1 = 0.0f;
      const int base = (2 * ly + dy) * 34 + 2 * lx;
      #pragma unroll
      for (int dx = 0; dx < 4; ++dx) {
        r0 += wx[dx] * s_tile0[base + dx];
        r1 += wx[dx] * s_tile1[base + dx];
      }
      acc0 += wy[dy] * r0;
      acc1 += wy[dy] * r1;
    }
    size_t o = (((size_t)b * 32 + 16 + c) * HW + oy) * HW + ox;
    out[o] = acc0 * inv;
    out[o + SZ] = acc1 * inv;
    __syncthreads();                               // s_src(next) ready; s_tile free
  }
}

// -------------------- K2: 3x3 conv over 50-ch bundle -> 2-ch adj --------------------
// LDS-staged halo (zero-filled), double-buffered with register round-trip (T14 split).
#define CHN 18                     // halo width (16 + 2)
#define CHE (CHN * CHN)            // 324 elements

__global__ void __launch_bounds__(256)
conv_kernel(const float* __restrict__ x,
            const float* __restrict__ warped,  // = out, ch 16..31
            const float* __restrict__ res,
            const float* __restrict__ Wc,      // [2,50,3,3]
            const float* __restrict__ bc,      // [2]
            float* __restrict__ adj)           // [B,2,512,512]
{
  __shared__ float sw[900];
  __shared__ float sh[2][CHE];

  const int tid = threadIdx.x;
  for (int i = tid; i < 900; i += 256) sw[i] = Wc[i];

  const int b = blockIdx.z;
  const int tx0 = blockIdx.x * 16, ty0 = blockIdx.y * 16;
  const int ty = tid >> 4, tx = tid & 15;

  float acc0 = bc[0];
  float acc1 = bc[1];

  const float* px = x + (size_t)b * 32 * SZ;
  const float* pw = warped + ((size_t)b * 32 + 16) * SZ;
  const float* pr = res + (size_t)b * 2 * SZ;

  #define PLANE(ic) ((ic) < 32 ? px + (size_t)(ic) * SZ \
                   : (ic) < 48 ? pw + (size_t)((ic) - 32) * SZ \
                   : pr + (size_t)((ic) - 48) * SZ)

  float rb0, rb1;
  {  // stage plane 0
    const float* pl = PLANE(0);
    rb0 = 0.f; rb1 = 0.f;
    int p = tid;
    { int ry = p / CHN, rx = p % CHN;
      int gy = ty0 - 1 + ry, gx = tx0 - 1 + rx;
      if ((unsigned)gy < (unsigned)HW && (unsigned)gx < (unsigned)HW) rb0 = pl[(size_t)gy * HW + gx]; }
    p = tid + 256;
    if (p < CHE) {
      int ry = p / CHN, rx = p % CHN;
      int gy = ty0 - 1 + ry, gx = tx0 - 1 + rx;
      if ((unsigned)gy < (unsigned)HW && (unsigned)gx < (unsigned)HW) rb1 = pl[(size_t)gy * HW + gx];
    }
    sh[0][tid] = rb0;
    if (tid + 256 < CHE) sh[0][tid + 256] = rb1;
  }

  for (int ic = 0; ic < 50; ++ic) {
    __syncthreads();                      // sh[ic&1] ready (and prev writes drained)
    if (ic < 49) {                        // issue next plane's loads before compute
      const float* pl = PLANE(ic + 1);
      rb0 = 0.f; rb1 = 0.f;
      int p = tid;
      { int ry = p / CHN, rx = p % CHN;
        int gy = ty0 - 1 + ry, gx = tx0 - 1 + rx;
        if ((unsigned)gy < (unsigned)HW && (unsigned)gx < (unsigned)HW) rb0 = pl[(size_t)gy * HW + gx]; }
      p = tid + 256;
      if (p < CHE) {
        int ry = p / CHN, rx = p % CHN;
        int gy = ty0 - 1 + ry, gx = tx0 - 1 + rx;
        if ((unsigned)gy < (unsigned)HW && (unsigned)gx < (unsigned)HW) rb1 = pl[(size_t)gy * HW + gx];
      }
    }

    const float* hp = sh[ic & 1];
    const float* w0 = &sw[ic * 9];
    const float* w1 = &sw[450 + ic * 9];
    #pragma unroll
    for (int ky = 0; ky < 3; ++ky) {
      #pragma unroll
      for (int kx = 0; kx < 3; ++kx) {
        float v = hp[(ty + ky) * CHN + tx + kx];
        acc0 += v * w0[ky * 3 + kx];
        acc1 += v * w1[ky * 3 + kx];
      }
    }

    if (ic < 49) {                        // write-late into the other buffer
      float* sd = sh[(ic + 1) & 1];
      sd[tid] = rb0;
      if (tid + 256 < CHE) sd[tid + 256] = rb1;
    }
  }
  #undef PLANE

  const int oy = ty0 + ty, ox = tx0 + tx;
  adj[((size_t)b * 2 + 0) * SZ + (size_t)oy * HW + ox] = acc0;
  adj[((size_t)b * 2 + 1) * SZ + (size_t)oy * HW + ox] = acc1;
}

// -------------------- K3: new_res = adj + downsample(warp(up(res), 2*up(adj))) --------------------
__global__ void __launch_bounds__(256)
new_res_kernel(const float* __restrict__ res,  // [B,2,512,512]
               const float* __restrict__ adj,  // [B,2,512,512]
               float* __restrict__ nres)       // [B,2,512,512]
{
  __shared__ float s_src0[36 * SRCP];
  __shared__ float s_src1[36 * SRCP];
  __shared__ float s_tile0[NPT];
  __shared__ float s_tile1[NPT];

  const int b = blockIdx.z;
  const int tx0 = blockIdx.x * 16, ty0 = blockIdx.y * 16;
  const int gx0 = tx0 * 2 - 1, gy0 = ty0 * 2 - 1;
  const int xo = tx0 - MARG, yo = ty0 - MARG;
  const int tid = threadIdx.x;

  const float* adjx = adj + (size_t)b * 2 * SZ;
  const float* adjy = adjx + SZ;
  const float* res0 = res + (size_t)b * 2 * SZ;
  const float* res1 = res0 + SZ;

  stage_pair(res0, res1, s_src0, s_src1, xo, yo, tid);

  PtTaps pt[K_PTS];
  compute_taps(adjx, adjy, gx0, gy0, xo, yo, tid, pt);

  const int ly = tid >> 4, lx = tid & 15;
  const int oy = ty0 + ly, ox = tx0 + lx;
  const float RW[4] = {0.25f, 0.75f, 0.75f, 0.25f};
  float wy[4], wx[4];
  float sumy = 0.f, sumx = 0.f;
  #pragma unroll
  for (int d = 0; d < 4; ++d) {
    int g = 2 * oy - 1 + d;
    wy[d] = ((unsigned)g < (unsigned)HW2) ? RW[d] : 0.0f; sumy += wy[d];
    g = 2 * ox - 1 + d;
    wx[d] = ((unsigned)g < (unsigned)HW2) ? RW[d] : 0.0f; sumx += wx[d];
  }
  const float inv = 1.0f / (sumy * sumx);

  __syncthreads();
  eval_round(s_src0, s_src1, s_tile0, s_tile1, res0, res1, pt, tid);
  __syncthreads();

  float acc0 = 0.0f, acc1 = 0.0f;
  #pragma unroll
  for (int dy = 0; dy < 4; ++dy) {
    float r0 = 0.0f, r1 = 0.0f;
    const int base = (2 * ly + dy) * 34 + 2 * lx;
    #pragma unroll
    for (int dx = 0; dx < 4; ++dx) {
      r0 += wx[dx] * s_tile0[base + dx];
      r1 += wx[dx] * s_tile1[base + dx];
    }
    acc0 += wy[dy] * r0;
    acc1 += wy[dy] * r1;
  }
  size_t o = ((size_t)b * 2) * SZ + (size_t)oy * HW + ox;
  nres[o]      = acc0 * inv + adjx[(size_t)oy * HW + ox];
  nres[o + SZ] = acc1 * inv + adjy[(size_t)oy * HW + ox];
}

extern "C" void kernel_launch(void* const* d_in, const int* in_sizes, int n_in,
                              void* d_out, int out_size, void* d_ws, size_t ws_size,
                              hipStream_t stream) {
  const float* x   = (const float*)d_in[0];  // [2,32,512,512] f32
  const float* res = (const float*)d_in[1];  // [2,2,512,512]  f32
  const float* Wc  = (const float*)d_in[2];  // [2,50,3,3]     f32
  const float* bc  = (const float*)d_in[3];  // [2]            f32
  float* out = (float*)d_out;                // [2,32,512,512] f32

  float* adj  = (float*)d_ws;                // [2,2,512,512]
  float* nres = adj + (size_t)2 * 2 * SZ;    // [2,2,512,512]

  // K0: src passthrough (out channels 0..15 per batch)
  {
    const size_t nvec = 2 * ((size_t)16 * SZ / 4);
    copy_src_kernel<<<dim3((unsigned)((nvec + 255) / 256)), dim3(256), 0, stream>>>(x, out);
  }

  dim3 tile_grid(32, 32, 2);

  // K1: warped_tgt (stage A) -> out channels 16..31 (fp32 staging for conv)
  warp_img_kernel<<<tile_grid, dim3(256), 0, stream>>>(x, res, out);

  // K2: conv3x3 over [x(0..31) | out(16..31) | res] -> adj
  conv_kernel<<<tile_grid, dim3(256), 0, stream>>>(x, out, res, Wc, bc, adj);

  // K3: new_res
  new_res_kernel<<<tile_grid, dim3(256), 0, stream>>>(res, adj, nres);

  // K4: hindsight warp -> out channels 16..31 (overwrites staging)
  warp_img_kernel<<<tile_grid, dim3(256), 0, stream>>>(x, nres, out);
}